// Round 1
// baseline (8091.839 us; speedup 1.0000x reference)
//
#include <hip/hip_runtime.h>
#include <math.h>

#define DDIM 256
#define KDIM 512
#define LN_EPS 1e-5f
#define BR 32
#define MT 16
#define JT 16

// ---------------------------------------------------------------------------
// Kernel 1: DpT[m][k] = LayerNorm_over_k( tanh(V @ H_drug^T) ) * g_d + b_d
// One block handles 4 drug columns m; 512 threads, thread k computes row k dot.
// ---------------------------------------------------------------------------
__global__ __launch_bounds__(512) void dp_kernel(
    const float* __restrict__ V, const float* __restrict__ Hd,
    const float* __restrict__ gd, const float* __restrict__ bd,
    float* __restrict__ DpT)
{
    __shared__ float h_sh[4][DDIM];
    __shared__ float red1[4][8];
    __shared__ float red2[4][8];

    const int t  = threadIdx.x;
    const int m0 = blockIdx.x * 4;

    for (int i = t; i < 4 * DDIM; i += 512)
        ((float*)h_sh)[i] = Hd[(size_t)m0 * DDIM + i];
    __syncthreads();

    const int k = t;
    float x0 = 0.f, x1 = 0.f, x2 = 0.f, x3 = 0.f;
    for (int j = 0; j < DDIM; j += 4) {
        float4 v4 = *(const float4*)(V + (size_t)k * DDIM + j);
        x0 += v4.x * h_sh[0][j] + v4.y * h_sh[0][j + 1] + v4.z * h_sh[0][j + 2] + v4.w * h_sh[0][j + 3];
        x1 += v4.x * h_sh[1][j] + v4.y * h_sh[1][j + 1] + v4.z * h_sh[1][j + 2] + v4.w * h_sh[1][j + 3];
        x2 += v4.x * h_sh[2][j] + v4.y * h_sh[2][j + 1] + v4.z * h_sh[2][j + 2] + v4.w * h_sh[2][j + 3];
        x3 += v4.x * h_sh[3][j] + v4.y * h_sh[3][j + 1] + v4.z * h_sh[3][j + 2] + v4.w * h_sh[3][j + 3];
    }
    float th[4];
    th[0] = tanhf(x0); th[1] = tanhf(x1); th[2] = tanhf(x2); th[3] = tanhf(x3);

    float s1[4], s2[4];
#pragma unroll
    for (int mi = 0; mi < 4; ++mi) { s1[mi] = th[mi]; s2[mi] = th[mi] * th[mi]; }
#pragma unroll
    for (int off = 32; off > 0; off >>= 1) {
#pragma unroll
        for (int mi = 0; mi < 4; ++mi) {
            s1[mi] += __shfl_xor(s1[mi], off, 64);
            s2[mi] += __shfl_xor(s2[mi], off, 64);
        }
    }
    const int wave = t >> 6;
    if ((t & 63) == 0) {
#pragma unroll
        for (int mi = 0; mi < 4; ++mi) { red1[mi][wave] = s1[mi]; red2[mi][wave] = s2[mi]; }
    }
    __syncthreads();

    const float gk = gd[k];
    const float bk = bd[k];
#pragma unroll
    for (int mi = 0; mi < 4; ++mi) {
        float sa = 0.f, sb = 0.f;
#pragma unroll
        for (int w = 0; w < 8; ++w) { sa += red1[mi][w]; sb += red2[mi][w]; }
        float mu  = sa * (1.f / KDIM);
        float var = sb * (1.f / KDIM) - mu * mu;
        float rs  = rsqrtf(var + LN_EPS);
        DpT[(size_t)(m0 + mi) * KDIM + k] = (th[mi] - mu) * rs * gk + bk;
    }
}

// ---------------------------------------------------------------------------
// Kernel 2: fused  a = LN(tanh(Hr@U))*q ; online softmax over  s = a @ DpT^T ;
//           out = P @ Hd.   One block = 32 RNA rows, 256 threads.
// Thread map: r = t>>3 (0..31), sub = t&7 owns k in [sub*64, sub*64+64).
// LDS overlay: step1 {h_sh[32][260], u_sh[16][512] swz} ;
//              step2 {dp_sh[16][512] swz, hd_sh[16][256] swz}
// XOR swizzle (float4 granularity) kills the 8-way bank conflict that the
// natural sub*64 addressing would cause (all subs on one bank quad).
// ---------------------------------------------------------------------------
__global__ __launch_bounds__(256, 2) void fused_kernel(
    const float* __restrict__ Hr, const float* __restrict__ U,
    const float* __restrict__ q,  const float* __restrict__ gr,
    const float* __restrict__ br, const float* __restrict__ DpT,
    const float* __restrict__ Hd, float* __restrict__ out, int M)
{
    __shared__ float smem[16512];   // 64.5 KB overlay
    __shared__ float gq_sh[KDIM];
    __shared__ float bq_sh[KDIM];

    const int t   = threadIdx.x;
    const int r   = t >> 3;
    const int sub = t & 7;
    const size_t row = (size_t)blockIdx.x * BR + r;

    float* h_sh  = smem;               // [32][260]  (pad 260 -> conflict-free h reads)
    float* u_sh  = smem + 32 * 260;    // [16][512]  swizzled
    float* dp_sh = smem;               // [16][512]  swizzled (step 2)
    float* hd_sh = smem + 8192;        // [16][256]  swizzled (step 2)

    for (int i = t; i < KDIM; i += 256) {
        gq_sh[i] = gr[i] * q[i];
        bq_sh[i] = br[i] * q[i];
    }
    // stage 32 H_rna rows (8192 floats)
#pragma unroll
    for (int i = 0; i < 8; ++i) {
        int flat = t * 4 + i * 1024;
        int rr = flat >> 8;
        int jj = flat & 255;
        float4 v = *(const float4*)(Hr + ((size_t)blockIdx.x * BR + rr) * DDIM + jj);
        *(float4*)(h_sh + rr * 260 + jj) = v;
    }

    float a[64];
#pragma unroll
    for (int i = 0; i < 64; ++i) a[i] = 0.f;

    // ---- step 1: x = Hr @ U, tiled over j ----
    for (int jt = 0; jt < DDIM / JT; ++jt) {
        __syncthreads();
#pragma unroll
        for (int i = 0; i < 8; ++i) {
            int flat = t * 4 + i * 1024;   // j*512 + k
            int dst  = (flat & ~63) | (((((flat >> 2) & 15) ^ ((flat >> 6) & 7))) << 2);
            float4 v = *(const float4*)(U + (size_t)jt * JT * KDIM + flat);
            *(float4*)(u_sh + dst) = v;
        }
        __syncthreads();
#pragma unroll
        for (int j = 0; j < JT; ++j) {
            float h = h_sh[r * 260 + jt * JT + j];
#pragma unroll
            for (int kk4 = 0; kk4 < 16; ++kk4) {
                float4 u = *(const float4*)(u_sh + (j << 9) + (sub << 6) + ((kk4 ^ sub) << 2));
                a[kk4 * 4 + 0] += h * u.x;
                a[kk4 * 4 + 1] += h * u.y;
                a[kk4 * 4 + 2] += h * u.z;
                a[kk4 * 4 + 3] += h * u.w;
            }
        }
    }

    // ---- tanh + LayerNorm over K + gate by q ----
    float s1 = 0.f, s2 = 0.f;
#pragma unroll
    for (int i = 0; i < 64; ++i) {
        a[i] = tanhf(a[i]);
        s1 += a[i];
        s2 += a[i] * a[i];
    }
#pragma unroll
    for (int off = 1; off < 8; off <<= 1) {
        s1 += __shfl_xor(s1, off, 8);
        s2 += __shfl_xor(s2, off, 8);
    }
    float mu  = s1 * (1.f / KDIM);
    float var = s2 * (1.f / KDIM) - mu * mu;
    float rs  = rsqrtf(var + LN_EPS);
#pragma unroll
    for (int i = 0; i < 64; ++i) {
        int k = sub * 64 + i;
        a[i] = (a[i] - mu) * rs * gq_sh[k] + bq_sh[k];
    }

    // ---- step 2: online softmax over M, accumulate out ----
    float o[32];
#pragma unroll
    for (int i = 0; i < 32; ++i) o[i] = 0.f;
    float mrun = -1e30f, lrun = 0.f;

    for (int m0 = 0; m0 < M; m0 += MT) {
        __syncthreads();
#pragma unroll
        for (int i = 0; i < 8; ++i) {                 // dp tile [16][512]
            int flat = t * 4 + i * 1024;
            int dst  = (flat & ~63) | (((((flat >> 2) & 15) ^ ((flat >> 6) & 7))) << 2);
            float4 v = *(const float4*)(DpT + (size_t)m0 * KDIM + flat);
            *(float4*)(dp_sh + dst) = v;
        }
#pragma unroll
        for (int i = 0; i < 4; ++i) {                 // hd tile [16][256]
            int flat = t * 4 + i * 1024;
            int dst  = (flat & ~31) | (((((flat >> 2) & 7) ^ ((flat >> 5) & 7))) << 2);
            float4 v = *(const float4*)(Hd + (size_t)m0 * DDIM + flat);
            *(float4*)(hd_sh + dst) = v;
        }
        __syncthreads();

        float ps[MT];
#pragma unroll
        for (int mm = 0; mm < MT; ++mm) {
            float acc = 0.f;
#pragma unroll
            for (int kk4 = 0; kk4 < 16; ++kk4) {
                float4 d4 = *(const float4*)(dp_sh + (mm << 9) + (sub << 6) + ((kk4 ^ sub) << 2));
                acc += a[kk4 * 4 + 0] * d4.x + a[kk4 * 4 + 1] * d4.y
                     + a[kk4 * 4 + 2] * d4.z + a[kk4 * 4 + 3] * d4.w;
            }
            ps[mm] = acc;
        }
        // butterfly over the 8 subs -> every sub holds full s[mm]
#pragma unroll
        for (int off = 1; off < 8; off <<= 1) {
#pragma unroll
            for (int mm = 0; mm < MT; ++mm) ps[mm] += __shfl_xor(ps[mm], off, 8);
        }
        // online softmax
        float cmax = ps[0];
#pragma unroll
        for (int mm = 1; mm < MT; ++mm) cmax = fmaxf(cmax, ps[mm]);
        float newm  = fmaxf(mrun, cmax);
        float alpha = __expf(mrun - newm);
        float lsum  = 0.f;
#pragma unroll
        for (int mm = 0; mm < MT; ++mm) { ps[mm] = __expf(ps[mm] - newm); lsum += ps[mm]; }
        lrun = lrun * alpha + lsum;
        mrun = newm;
#pragma unroll
        for (int i = 0; i < 32; ++i) o[i] *= alpha;
        // PV accumulate: o[c] += p_m * Hd[m][c],  c = sub*32 + cc
#pragma unroll
        for (int mm = 0; mm < MT; ++mm) {
            float p = ps[mm];
#pragma unroll
            for (int cc4 = 0; cc4 < 8; ++cc4) {
                float4 h4 = *(const float4*)(hd_sh + (mm << 8) + (sub << 5) + ((cc4 ^ sub) << 2));
                o[cc4 * 4 + 0] += p * h4.x;
                o[cc4 * 4 + 1] += p * h4.y;
                o[cc4 * 4 + 2] += p * h4.z;
                o[cc4 * 4 + 3] += p * h4.w;
            }
        }
    }

    const float inv = 1.f / lrun;
#pragma unroll
    for (int cc4 = 0; cc4 < 8; ++cc4) {
        float4 v;
        v.x = o[cc4 * 4 + 0] * inv;
        v.y = o[cc4 * 4 + 1] * inv;
        v.z = o[cc4 * 4 + 2] * inv;
        v.w = o[cc4 * 4 + 3] * inv;
        *(float4*)(out + row * DDIM + sub * 32 + cc4 * 4) = v;
    }
}

extern "C" void kernel_launch(void* const* d_in, const int* in_sizes, int n_in,
                              void* d_out, int out_size, void* d_ws, size_t ws_size,
                              hipStream_t stream)
{
    const float* Hr = (const float*)d_in[0];
    const float* Hd = (const float*)d_in[1];
    const float* U  = (const float*)d_in[2];
    const float* V  = (const float*)d_in[3];
    const float* q  = (const float*)d_in[4];
    const float* gr = (const float*)d_in[5];
    const float* br = (const float*)d_in[6];
    const float* gd = (const float*)d_in[7];
    const float* bd = (const float*)d_in[8];
    float* out = (float*)d_out;

    const int N = in_sizes[0] / DDIM;   // 65536
    const int M = in_sizes[1] / DDIM;   // 2048

    float* DpT = (float*)d_ws;          // [M][K] fp32, 4 MB

    dp_kernel<<<dim3(M / 4), dim3(512), 0, stream>>>(V, Hd, gd, bd, DpT);
    fused_kernel<<<dim3(N / BR), dim3(256), 0, stream>>>(Hr, U, q, gr, br, DpT, Hd, out, M);
}

// Round 2
// 865.380 us; speedup vs baseline: 9.3506x; 9.3506x over previous
//
#include <hip/hip_runtime.h>
#include <math.h>

#define LN_EPS 1e-5f

typedef _Float16 h8 __attribute__((ext_vector_type(8)));
typedef _Float16 h4 __attribute__((ext_vector_type(4)));
typedef float f32x4 __attribute__((ext_vector_type(4)));

#define MFMA16(A,B,C) __builtin_amdgcn_mfma_f32_16x16x32_f16(A,B,C,0,0,0)

__device__ __forceinline__ float fast_tanh(float x){
    float e = __expf(2.f*x);
    return 1.f - 2.f/(e+1.f);
}

// ---------------------------------------------------------------------------
// dp_kernel: dp[m][k] = LN_k(tanh(V@Hd^T))*g_d+b_d, written as fp16 into the
// B-fragment-packed layout for mfma_f32_16x16x32_f16:
//   slot[mt][kk][lane][j] = dp[16*mt + (lane&15)][32*kk + 8*(lane>>4) + j]
// ---------------------------------------------------------------------------
__global__ __launch_bounds__(512) void dp_kernel(
    const float* __restrict__ V, const float* __restrict__ Hd,
    const float* __restrict__ gd, const float* __restrict__ bd,
    _Float16* __restrict__ dp_pack)
{
    __shared__ float h_sh[4][256];
    __shared__ float red1[4][8];
    __shared__ float red2[4][8];

    const int t  = threadIdx.x;
    const int m0 = blockIdx.x * 4;

    for (int i = t; i < 4 * 256; i += 512)
        ((float*)h_sh)[i] = Hd[(size_t)m0 * 256 + i];
    __syncthreads();

    const int k = t;
    float x0 = 0.f, x1 = 0.f, x2 = 0.f, x3 = 0.f;
    for (int j = 0; j < 256; j += 4) {
        float4 v4 = *(const float4*)(V + (size_t)k * 256 + j);
        x0 += v4.x * h_sh[0][j] + v4.y * h_sh[0][j + 1] + v4.z * h_sh[0][j + 2] + v4.w * h_sh[0][j + 3];
        x1 += v4.x * h_sh[1][j] + v4.y * h_sh[1][j + 1] + v4.z * h_sh[1][j + 2] + v4.w * h_sh[1][j + 3];
        x2 += v4.x * h_sh[2][j] + v4.y * h_sh[2][j + 1] + v4.z * h_sh[2][j + 2] + v4.w * h_sh[2][j + 3];
        x3 += v4.x * h_sh[3][j] + v4.y * h_sh[3][j + 1] + v4.z * h_sh[3][j + 2] + v4.w * h_sh[3][j + 3];
    }
    float th[4];
    th[0] = tanhf(x0); th[1] = tanhf(x1); th[2] = tanhf(x2); th[3] = tanhf(x3);

    float s1[4], s2[4];
#pragma unroll
    for (int mi = 0; mi < 4; ++mi) { s1[mi] = th[mi]; s2[mi] = th[mi] * th[mi]; }
#pragma unroll
    for (int off = 32; off > 0; off >>= 1) {
#pragma unroll
        for (int mi = 0; mi < 4; ++mi) {
            s1[mi] += __shfl_xor(s1[mi], off, 64);
            s2[mi] += __shfl_xor(s2[mi], off, 64);
        }
    }
    const int wave = t >> 6;
    if ((t & 63) == 0) {
#pragma unroll
        for (int mi = 0; mi < 4; ++mi) { red1[mi][wave] = s1[mi]; red2[mi][wave] = s2[mi]; }
    }
    __syncthreads();

    const float gk = gd[k];
    const float bk = bd[k];
#pragma unroll
    for (int mi = 0; mi < 4; ++mi) {
        float sa = 0.f, sb = 0.f;
#pragma unroll
        for (int ww = 0; ww < 8; ++ww) { sa += red1[mi][ww]; sb += red2[mi][ww]; }
        float mu  = sa * (1.f / 512.f);
        float var = sb * (1.f / 512.f) - mu * mu;
        float rs  = rsqrtf(var + LN_EPS);
        float a   = (th[mi] - mu) * rs * gk + bk;
        int m  = m0 + mi;
        int mt = m >> 4, kk = k >> 5, ln = (m & 15) + 16 * ((k >> 3) & 3), j = k & 7;
        dp_pack[(size_t)((mt * 16 + kk) * 64 + ln) * 8 + j] = (_Float16)a;
    }
}

// hd_pack[nt][kk][lane][j] = Hd[32*kk + 8*(lane>>4)+j][16*nt + (lane&15)]  (fp16)
__global__ void pack_hd_kernel(const float* __restrict__ Hd, _Float16* __restrict__ hp)
{
    int m = blockIdx.x, c = threadIdx.x;
    float v = Hd[(size_t)m * 256 + c];
    int nt = c >> 4, kk = m >> 5, ln = (c & 15) + 16 * ((m >> 3) & 3), j = m & 7;
    hp[(size_t)((nt * 64 + kk) * 64 + ln) * 8 + j] = (_Float16)v;
}

// u_pack[nt][kd][lane][jj] = U[32*kd + 8*(lane>>4)+jj][16*nt + (lane&15)]  hi/lo fp16
__global__ void pack_u_kernel(const float* __restrict__ U,
                              _Float16* __restrict__ uh, _Float16* __restrict__ ul)
{
    int jd = blockIdx.x, n = threadIdx.x;
    float v = U[(size_t)jd * 512 + n];
    _Float16 hi = (_Float16)v;
    _Float16 lo = (_Float16)(v - (float)hi);
    int nt = n >> 4, kd = jd >> 5, ln = (n & 15) + 16 * ((jd >> 3) & 3), jj = jd & 7;
    int idx = ((nt * 8 + kd) * 64 + ln) * 8 + jj;
    uh[idx] = hi; ul[idx] = lo;
}

// ---------------------------------------------------------------------------
// Main kernel: 64 rows/block, 256 threads (4 waves), MFMA 16x16x32 f16.
// Phase A: x = Hr@U (3-product fp16 split) -> tanh -> LN -> *q -> a_pack (LDS)
// M-loop (8 iters x 256 cols): S = a@dp^T (1 MFMA product), online softmax,
// P -> LDS (A-frag layout), O += P@Hd.
// ---------------------------------------------------------------------------
__global__ __launch_bounds__(256, 1) void attn_kernel(
    const float* __restrict__ Hr, const float* __restrict__ q,
    const float* __restrict__ gr, const float* __restrict__ br,
    const _Float16* __restrict__ u_hi, const _Float16* __restrict__ u_lo,
    const _Float16* __restrict__ dp_pack, const _Float16* __restrict__ hd_pack,
    float* __restrict__ out)
{
    __shared__ __align__(16) _Float16 lds0[32768];   // 64KB: hr hi/lo, then a_pack
    __shared__ __align__(16) _Float16 p_pack[16384]; // 32KB
    __shared__ __align__(16) float stats[2][64][4];  // 2KB

    const int t    = threadIdx.x;
    const int w    = t >> 6;
    const int lane = t & 63;
    const int q4   = lane >> 4;
    const int l15  = lane & 15;
    const int blk  = blockIdx.x;

    _Float16* hr_hi  = lds0;
    _Float16* hr_lo  = lds0 + 16384;
    _Float16* a_pack = lds0;

    // per-thread LN gate params for this thread's 8 columns
    float gq[8], bq[8];
#pragma unroll
    for (int i = 0; i < 8; ++i) {
        int c = w * 128 + 16 * i + l15;
        gq[i] = gr[c] * q[c];
        bq[i] = br[c] * q[c];
    }

    // ---- stage Hr rows -> hi/lo A-fragments in LDS (coalesced global reads) ----
    const float* HrB = Hr + (size_t)blk * 64 * 256;
#pragma unroll
    for (int ii = 0; ii < 16; ++ii) {
        int flat = (t + 256 * ii) * 4;
        int r = flat >> 8, c = flat & 255;
        float4 v = *(const float4*)(HrB + flat);
        int base = (((r >> 4) * 8 + (c >> 5)) * 64 + ((r & 15) + 16 * ((c >> 3) & 3))) * 8 + (c & 7);
        h4 hi, lo;
        hi[0] = (_Float16)v.x; lo[0] = (_Float16)(v.x - (float)hi[0]);
        hi[1] = (_Float16)v.y; lo[1] = (_Float16)(v.y - (float)hi[1]);
        hi[2] = (_Float16)v.z; lo[2] = (_Float16)(v.z - (float)hi[2]);
        hi[3] = (_Float16)v.w; lo[3] = (_Float16)(v.w - (float)hi[3]);
        *(h4*)(hr_hi + base) = hi;
        *(h4*)(hr_lo + base) = lo;
    }
    __syncthreads();

    // ---- phase A: x[rt][ci] = Hr@U, split fp16 3-product ----
    f32x4 x[4][8];
#pragma unroll
    for (int rt = 0; rt < 4; ++rt)
#pragma unroll
        for (int ci = 0; ci < 8; ++ci) x[rt][ci] = (f32x4)(0.f);

#pragma unroll
    for (int kd = 0; kd < 8; ++kd) {
        h8 ah[4], al[4];
#pragma unroll
        for (int rt = 0; rt < 4; ++rt) {
            int idx = ((rt * 8 + kd) * 64 + lane) * 8;
            ah[rt] = *(h8*)(hr_hi + idx);
            al[rt] = *(h8*)(hr_lo + idx);
        }
        h8 bh[8], bl[8];
#pragma unroll
        for (int ci = 0; ci < 8; ++ci) {
            int idx = (((8 * w + ci) * 8 + kd) * 64 + lane) * 8;
            bh[ci] = *(const h8*)(u_hi + idx);
            bl[ci] = *(const h8*)(u_lo + idx);
        }
#pragma unroll
        for (int rt = 0; rt < 4; ++rt)
#pragma unroll
            for (int ci = 0; ci < 8; ++ci) x[rt][ci] = MFMA16(ah[rt], bh[ci], x[rt][ci]);
#pragma unroll
        for (int rt = 0; rt < 4; ++rt)
#pragma unroll
            for (int ci = 0; ci < 8; ++ci) x[rt][ci] = MFMA16(ah[rt], bl[ci], x[rt][ci]);
#pragma unroll
        for (int rt = 0; rt < 4; ++rt)
#pragma unroll
            for (int ci = 0; ci < 8; ++ci) x[rt][ci] = MFMA16(al[rt], bh[ci], x[rt][ci]);
    }

    // ---- tanh + LN stats ----
    float s1[4][4], s2[4][4];
#pragma unroll
    for (int rt = 0; rt < 4; ++rt)
#pragma unroll
        for (int e = 0; e < 4; ++e) { s1[rt][e] = 0.f; s2[rt][e] = 0.f; }
#pragma unroll
    for (int rt = 0; rt < 4; ++rt)
#pragma unroll
        for (int ci = 0; ci < 8; ++ci)
#pragma unroll
            for (int e = 0; e < 4; ++e) {
                float th = fast_tanh(x[rt][ci][e]);
                x[rt][ci][e] = th;
                s1[rt][e] += th;
                s2[rt][e] += th * th;
            }
#pragma unroll
    for (int off = 1; off < 16; off <<= 1)
#pragma unroll
        for (int rt = 0; rt < 4; ++rt)
#pragma unroll
            for (int e = 0; e < 4; ++e) {
                s1[rt][e] += __shfl_xor(s1[rt][e], off, 64);
                s2[rt][e] += __shfl_xor(s2[rt][e], off, 64);
            }
    if (l15 == 0) {
#pragma unroll
        for (int rt = 0; rt < 4; ++rt)
#pragma unroll
            for (int e = 0; e < 4; ++e) {
                int row = rt * 16 + q4 * 4 + e;
                stats[0][row][w] = s1[rt][e];
                stats[1][row][w] = s2[rt][e];
            }
    }
    __syncthreads();

    float mu[4][4], rs_[4][4];
#pragma unroll
    for (int rt = 0; rt < 4; ++rt)
#pragma unroll
        for (int e = 0; e < 4; ++e) {
            int row = rt * 16 + q4 * 4 + e;
            f32x4 v1 = *(f32x4*)&stats[0][row][0];
            f32x4 v2 = *(f32x4*)&stats[1][row][0];
            float S1 = v1[0] + v1[1] + v1[2] + v1[3];
            float S2 = v2[0] + v2[1] + v2[2] + v2[3];
            float m  = S1 * (1.f / 512.f);
            float va = S2 * (1.f / 512.f) - m * m;
            mu[rt][e]  = m;
            rs_[rt][e] = rsqrtf(va + LN_EPS);
        }

    // ---- LN affine + gate, write a_pack (overwrites hr region) ----
#pragma unroll
    for (int rt = 0; rt < 4; ++rt)
#pragma unroll
        for (int ci = 0; ci < 8; ++ci)
#pragma unroll
            for (int e = 0; e < 4; ++e) {
                int mrow = q4 * 4 + e;
                int c = w * 128 + 16 * ci + l15;
                float a = (x[rt][ci][e] - mu[rt][e]) * rs_[rt][e] * gq[ci] + bq[ci];
                a_pack[((rt * 16 + (c >> 5)) * 64 + (mrow + 16 * ((c >> 3) & 3))) * 8 + (c & 7)] =
                    (_Float16)a;
            }
    __syncthreads();

    // ---- flash M-loop ----
    f32x4 o[4][4];
#pragma unroll
    for (int rt = 0; rt < 4; ++rt)
#pragma unroll
        for (int nc = 0; nc < 4; ++nc) o[rt][nc] = (f32x4)(0.f);
    float mrun[4][4], lrun[4][4];
#pragma unroll
    for (int rt = 0; rt < 4; ++rt)
#pragma unroll
        for (int e = 0; e < 4; ++e) { mrun[rt][e] = -3.0e38f; lrun[rt][e] = 0.f; }

    for (int it = 0; it < 8; ++it) {
        // S = a @ dp^T  (single fp16 product)
        f32x4 s[4][4];
#pragma unroll
        for (int rt = 0; rt < 4; ++rt)
#pragma unroll
            for (int ct = 0; ct < 4; ++ct) s[rt][ct] = (f32x4)(0.f);
#pragma unroll
        for (int kk = 0; kk < 16; ++kk) {
            h8 af[4];
#pragma unroll
            for (int rt = 0; rt < 4; ++rt)
                af[rt] = *(h8*)(a_pack + ((rt * 16 + kk) * 64 + lane) * 8);
            h8 bf[4];
#pragma unroll
            for (int ct = 0; ct < 4; ++ct) {
                int mt = it * 16 + w * 4 + ct;
                bf[ct] = *(const h8*)(dp_pack + (size_t)((mt * 16 + kk) * 64 + lane) * 8);
            }
#pragma unroll
            for (int rt = 0; rt < 4; ++rt)
#pragma unroll
                for (int ct = 0; ct < 4; ++ct) s[rt][ct] = MFMA16(af[rt], bf[ct], s[rt][ct]);
        }

        // row-max partial (over this wave's 64 cols)
        float pm[4][4];
#pragma unroll
        for (int rt = 0; rt < 4; ++rt)
#pragma unroll
            for (int e = 0; e < 4; ++e) {
                float m0 = fmaxf(fmaxf(s[rt][0][e], s[rt][1][e]), fmaxf(s[rt][2][e], s[rt][3][e]));
                pm[rt][e] = m0;
            }
#pragma unroll
        for (int off = 1; off < 16; off <<= 1)
#pragma unroll
            for (int rt = 0; rt < 4; ++rt)
#pragma unroll
                for (int e = 0; e < 4; ++e)
                    pm[rt][e] = fmaxf(pm[rt][e], __shfl_xor(pm[rt][e], off, 64));
        if (l15 == 0) {
#pragma unroll
            for (int rt = 0; rt < 4; ++rt)
#pragma unroll
                for (int e = 0; e < 4; ++e)
                    stats[0][rt * 16 + q4 * 4 + e][w] = pm[rt][e];
        }
        __syncthreads();   // b1: maxes visible

        float alpha[4][4], mnew[4][4], psum[4][4];
#pragma unroll
        for (int rt = 0; rt < 4; ++rt)
#pragma unroll
            for (int e = 0; e < 4; ++e) {
                int row = rt * 16 + q4 * 4 + e;
                f32x4 v = *(f32x4*)&stats[0][row][0];
                float mn = fmaxf(fmaxf(v[0], v[1]), fmaxf(v[2], v[3]));
                mn = fmaxf(mn, mrun[rt][e]);
                alpha[rt][e] = __expf(mrun[rt][e] - mn);
                mnew[rt][e]  = mn;
                psum[rt][e]  = 0.f;
            }
        // exp + partial sums
#pragma unroll
        for (int rt = 0; rt < 4; ++rt)
#pragma unroll
            for (int ct = 0; ct < 4; ++ct)
#pragma unroll
                for (int e = 0; e < 4; ++e) {
                    float p = __expf(s[rt][ct][e] - mnew[rt][e]);
                    s[rt][ct][e] = p;
                    psum[rt][e] += p;
                }
#pragma unroll
        for (int off = 1; off < 16; off <<= 1)
#pragma unroll
            for (int rt = 0; rt < 4; ++rt)
#pragma unroll
                for (int e = 0; e < 4; ++e)
                    psum[rt][e] += __shfl_xor(psum[rt][e], off, 64);
        if (l15 == 0) {
#pragma unroll
            for (int rt = 0; rt < 4; ++rt)
#pragma unroll
                for (int e = 0; e < 4; ++e)
                    stats[1][rt * 16 + q4 * 4 + e][w] = psum[rt][e];
        }
        // write P into A-fragment layout (fp16)
#pragma unroll
        for (int rt = 0; rt < 4; ++rt)
#pragma unroll
            for (int ct = 0; ct < 4; ++ct)
#pragma unroll
                for (int e = 0; e < 4; ++e) {
                    int mrow = q4 * 4 + e;
                    int col  = 64 * w + 16 * ct + l15;
                    p_pack[((rt * 8 + (col >> 5)) * 64 + (mrow + 16 * ((col >> 3) & 3))) * 8 + (col & 7)] =
                        (_Float16)s[rt][ct][e];
                }
        // rescale O
#pragma unroll
        for (int rt = 0; rt < 4; ++rt)
#pragma unroll
            for (int nc = 0; nc < 4; ++nc)
#pragma unroll
                for (int e = 0; e < 4; ++e) o[rt][nc][e] *= alpha[rt][e];
        __syncthreads();   // b2: sums + P visible

#pragma unroll
        for (int rt = 0; rt < 4; ++rt)
#pragma unroll
            for (int e = 0; e < 4; ++e) {
                int row = rt * 16 + q4 * 4 + e;
                f32x4 v = *(f32x4*)&stats[1][row][0];
                lrun[rt][e] = lrun[rt][e] * alpha[rt][e] + (v[0] + v[1] + v[2] + v[3]);
                mrun[rt][e] = mnew[rt][e];
            }

        // O += P @ Hd
#pragma unroll
        for (int kp = 0; kp < 8; ++kp) {
            h8 pf[4];
#pragma unroll
            for (int rt = 0; rt < 4; ++rt)
                pf[rt] = *(h8*)(p_pack + ((rt * 8 + kp) * 64 + lane) * 8);
            h8 hf[4];
#pragma unroll
            for (int nc = 0; nc < 4; ++nc) {
                int nt = 4 * w + nc;
                hf[nc] = *(const h8*)(hd_pack + (size_t)((nt * 64 + it * 8 + kp) * 64 + lane) * 8);
            }
#pragma unroll
            for (int rt = 0; rt < 4; ++rt)
#pragma unroll
                for (int nc = 0; nc < 4; ++nc) o[rt][nc] = MFMA16(pf[rt], hf[nc], o[rt][nc]);
        }
        __syncthreads();   // b3: PV done before next iter overwrites p_pack/stats
    }

    // ---- epilogue: out = O / l ----
    float inv[4][4];
#pragma unroll
    for (int rt = 0; rt < 4; ++rt)
#pragma unroll
        for (int e = 0; e < 4; ++e) inv[rt][e] = 1.f / lrun[rt][e];
#pragma unroll
    for (int rt = 0; rt < 4; ++rt)
#pragma unroll
        for (int nc = 0; nc < 4; ++nc)
#pragma unroll
            for (int e = 0; e < 4; ++e) {
                int row = rt * 16 + q4 * 4 + e;
                int c   = (4 * w + nc) * 16 + l15;
                out[((size_t)blk * 64 + row) * 256 + c] = o[rt][nc][e] * inv[rt][e];
            }
}

extern "C" void kernel_launch(void* const* d_in, const int* in_sizes, int n_in,
                              void* d_out, int out_size, void* d_ws, size_t ws_size,
                              hipStream_t stream)
{
    const float* Hr = (const float*)d_in[0];
    const float* Hd = (const float*)d_in[1];
    const float* U  = (const float*)d_in[2];
    const float* V  = (const float*)d_in[3];
    const float* q  = (const float*)d_in[4];
    const float* gr = (const float*)d_in[5];
    const float* br = (const float*)d_in[6];
    const float* gd = (const float*)d_in[7];
    const float* bd = (const float*)d_in[8];
    float* out = (float*)d_out;

    const int N = in_sizes[0] / 256;   // 65536
    const int M = in_sizes[1] / 256;   // 2048

    char* ws = (char*)d_ws;
    _Float16* dp_pack = (_Float16*)ws;                               // 2 MB
    _Float16* hd_pack = (_Float16*)(ws + (2u << 20));                // 1 MB
    _Float16* u_hi    = (_Float16*)(ws + (3u << 20));                // 256 KB
    _Float16* u_lo    = (_Float16*)(ws + (3u << 20) + (256u << 10)); // 256 KB

    dp_kernel<<<dim3(M / 4), dim3(512), 0, stream>>>(V, Hd, gd, bd, dp_pack);
    pack_hd_kernel<<<dim3(M), dim3(256), 0, stream>>>(Hd, hd_pack);
    pack_u_kernel<<<dim3(256), dim3(512), 0, stream>>>(U, u_hi, u_lo);
    attn_kernel<<<dim3(N / 64), dim3(256), 0, stream>>>(Hr, q, gr, br, u_hi, u_lo,
                                                        dp_pack, hd_pack, out);
}